// Round 2
// baseline (699.217 us; speedup 1.0000x reference)
//
#include <hip/hip_runtime.h>

#define C_S 384
#define C_Z 128
#define N_SEQ 1024

// Fused single-kernel version — no workspace, no second launch.
//
// Each block owns a TN x TM = 32 x 64 tile of the 1024x1024 output.
// Phase 1: the 96 row/col projections the tile needs (32 si dots + 64 sj dots,
//          length-384 each) are computed into LDS by wave-wide dot+butterfly.
//          Redundant FLOPs vs a separate kernel: 96*768 / (2048*256) = +14%,
//          and the s-rows involved are L2-resident (s is 1.5 MiB total).
// Phase 2: stream the tile's 1 MiB of z with the 8-pair inner loop:
//          pair = 2 outputs = 256 consecutive floats; lanes 0-31 -> even m,
//          lanes 32-63 -> odd m; 8 independent float4 loads (8 KiB contiguous)
//          in flight per wave-iteration before any reduction.
// Grid: (1024/32)*(1024/64) = 512 blocks, 4 waves each -> 2 blocks/CU,
// 8 waves/CU * 8 KiB = 64 KiB in flight per CU >> the ~9 KiB needed to cover
// ~900-cycle HBM latency at 10.25 B/cyc/CU (6.3 TB/s).

#define TN 32
#define TM 64
#define U_PAIRS 8   // 8 pairs = 16 outputs = 8 KiB of z per inner iteration

__global__ __launch_bounds__(256) void fused_contact(const float* __restrict__ s,
                                                     const float* __restrict__ z,
                                                     const float* __restrict__ W,
                                                     const float* __restrict__ b,
                                                     float* __restrict__ out) {
    __shared__ float si_l[TN];
    __shared__ float sj_l[TM];

    const int lane = threadIdx.x & 63;
    const int wave = threadIdx.x >> 6;

    const int bid = blockIdx.x;
    const int n0 = (bid >> 4) * TN;   // 16 m-tiles per n-band
    const int m0 = (bid & 15) * TM;

    // ---- Phase 1: si/sj projections for this tile -> LDS.
    // 96 tasks (t<32: si[n0+t] with Wi; t>=32: sj[m0+t-32] with Wj, +bias).
    // 24 sequential wave-wide dots per wave.
    for (int t = wave * 24; t < wave * 24 + 24; ++t) {
        const bool is_j = (t >= TN);
        const int row = is_j ? (m0 + t - TN) : (n0 + t);
        const float* srow = s + (size_t)row * C_S;
        const float* Wp = W + (is_j ? C_S : 0);
        float acc = 0.f;
#pragma unroll
        for (int d = lane; d < C_S; d += 64) {
            acc += srow[d] * Wp[d];
        }
#pragma unroll
        for (int mask = 32; mask >= 1; mask >>= 1) {
            acc += __shfl_xor(acc, mask);
        }
        if (lane == 0) {
            if (is_j) sj_l[t - TN] = acc + b[0];
            else      si_l[t] = acc;
        }
    }
    __syncthreads();

    // ---- Phase 2: stream the z tile.
    const int half = lane >> 5;        // which output of the pair
    const int l = lane & 31;           // position within the 32-lane group
    const float4 wz = *(const float4*)(W + 2 * C_S + 4 * l);

    // wave w handles rows n = n0 + 8w .. n0 + 8w + 7
    for (int r = 0; r < 8; ++r) {
        const int nloc = wave * 8 + r;
        const int n = n0 + nloc;
        const float si_v = si_l[nloc];
        const float* zrow = z + ((size_t)n * N_SEQ + m0) * C_Z;

        for (int c4 = 0; c4 < TM / (2 * U_PAIRS); ++c4) {   // 4 chunks of 8 KiB
            const float* zb = zrow + c4 * (U_PAIRS * 256) + 4 * lane;

            float4 z4[U_PAIRS];
#pragma unroll
            for (int u = 0; u < U_PAIRS; ++u) {
                z4[u] = *(const float4*)(zb + u * 256);
            }

            float p[U_PAIRS];
#pragma unroll
            for (int u = 0; u < U_PAIRS; ++u) {
                p[u] = z4[u].x * wz.x + z4[u].y * wz.y + z4[u].z * wz.z + z4[u].w * wz.w;
            }

            // reduce across each 32-lane half; masks <=16 stay within the half
#pragma unroll
            for (int mask = 16; mask >= 1; mask >>= 1) {
#pragma unroll
                for (int u = 0; u < U_PAIRS; ++u) {
                    p[u] += __shfl_xor(p[u], mask);
                }
            }

            if (l == 0) {
#pragma unroll
                for (int u = 0; u < U_PAIRS; ++u) {
                    const int mloc = c4 * (2 * U_PAIRS) + 2 * u + half;
                    out[(size_t)n * N_SEQ + m0 + mloc] = p[u] + si_v + sj_l[mloc];
                }
            }
        }
    }
}

extern "C" void kernel_launch(void* const* d_in, const int* in_sizes, int n_in,
                              void* d_out, int out_size, void* d_ws, size_t ws_size,
                              hipStream_t stream) {
    const float* s = (const float*)d_in[0];   // (1,1024,384)
    const float* z = (const float*)d_in[1];   // (1,1024,1024,128)
    const float* W = (const float*)d_in[2];   // (1,896)
    const float* b = (const float*)d_in[3];   // (1,)
    float* out = (float*)d_out;               // (1,1024,1024,1)

    (void)d_ws; (void)ws_size;                // workspace intentionally unused

    const int blocks = (N_SEQ / TN) * (N_SEQ / TM);   // 512
    fused_contact<<<blocks, 256, 0, stream>>>(s, z, W, b, out);
}